// Round 7
// baseline (371.871 us; speedup 1.0000x reference)
//
#include <hip/hip_runtime.h>
#include <hip/hip_cooperative_groups.h>
#include <math.h>

namespace cg = cooperative_groups;

// ---------------- problem constants ----------------
constexpr int BATCH   = 8;
constexpr int NUM_CLS = 80;
constexpr int N0 = 19 * 19 * 3;   // 1083  (stride 32)
constexpr int N1 = 38 * 38 * 3;   // 4332  (stride 16)
constexpr int N2 = 76 * 76 * 3;   // 17328 (stride 8)
constexpr int OFF1 = N0;          // 1083
constexpr int OFF2 = N0 + N1;     // 5415
constexpr int NTOT = N0 + N1 + N2; // 22743 per image
constexpr int TOPN = 1000;
constexpr int NSEL = 3 * TOPN;    // 3000 per image
constexpr int MAXDET = 100;
constexpr float MIN_SCORE_F = 0.05f;
constexpr int IMG_MAX = 607;
constexpr int WPR = (NSEL + 63) / 64;      // 47 u64 words per mask row
constexpr int NTASK = WPR * (WPR + 1) / 2; // 1128 iou tile-tasks per image
constexpr int NBIN  = 4096;
constexpr int STCAP = 2048;
constexpr int WIN   = 8;

constexpr int GRID = 256;
constexpr int BLK  = 512;
constexpr int NTHR = GRID * BLK;          // 131072
constexpr int NWAVE = NTHR / 64;          // 2048

__device__ __forceinline__ float sigmoidf_(float x) {
    return 1.0f / (1.0f + expf(-x));
}

struct MegaArgs {
    const float *obj0, *reg0, *cls0;
    const float *obj1, *reg1, *cls1;
    const float *obj2, *reg2, *cls2;
    unsigned long long* decKey; float* decC; float* decB;
    float* selC; float* selB; unsigned long long* selKey;
    int* gflagImg; int* fbCursor;
    float* srtS; float* srtC; float* srtB;
    unsigned long long* gmask;
    float* out;
};

union MegaSmem {
    struct {
        unsigned hist[NBIN];               // 16 KB (counts, then cursor/cnt)
        unsigned cum[NBIN];                // 16 KB (strictly-higher counts)
        unsigned chunkH[NBIN / 64];        // 256 B
        unsigned long long stKey[STCAP];   // 16 KB
        int stIdx[STCAP];                  // 8 KB
        int sTot, sOvf, sBstar, sNeed;
    } sel;                                  // 57.6 KB
    struct { unsigned long long ks[NSEL]; } mrg; // 24 KB
    struct {
        unsigned long long validLds[WPR];
        int keptIdx[MAXDET];
        int sPos;
    } res;
};

__global__ __launch_bounds__(BLK) void k_mega(MegaArgs A)
{
    cg::grid_group grid = cg::this_grid();
    __shared__ MegaSmem sm;
    const int tid  = threadIdx.x;
    const int gtid = blockIdx.x * BLK + tid;

    // ================= Phase A: decode (analytic anchors) =================
    // anchors = (gx, gy, AW*st, AH*st, st), st = power of 2 ->
    // exp(r)*(AW*st)/st == exp(r)*AW bit-exactly.
    if (gtid < 8)  A.gflagImg[gtid] = 0;
    if (gtid < 24) A.fbCursor[gtid] = 0;
    for (int idx = gtid; idx < BATCH * NTOT; idx += NTHR) {
        int b  = idx / NTOT;
        int na = idx - b * NTOT;

        const float *obj, *reg, *cls;
        int Nl, n, g;
        float stf, AW0, AW1, AW2, AH0, AH1, AH2;
        if (na < OFF1) {
            obj = A.obj0; reg = A.reg0; cls = A.cls0; Nl = N0; n = na; g = 19; stf = 32.f;
            AW0 = 116.f; AW1 = 156.f; AW2 = 373.f; AH0 = 90.f; AH1 = 198.f; AH2 = 326.f;
        } else if (na < OFF2) {
            obj = A.obj1; reg = A.reg1; cls = A.cls1; Nl = N1; n = na - OFF1; g = 38; stf = 16.f;
            AW0 = 30.f; AW1 = 62.f; AW2 = 59.f; AH0 = 61.f; AH1 = 45.f; AH2 = 119.f;
        } else {
            obj = A.obj2; reg = A.reg2; cls = A.cls2; Nl = N2; n = na - OFF2; g = 76; stf = 8.f;
            AW0 = 10.f; AW1 = 16.f; AW2 = 33.f; AH0 = 13.f; AH1 = 30.f; AH2 = 23.f;
        }
        int g3  = g * 3;
        int gy  = n / g3;
        int rem = n - gy * g3;
        int gx  = rem / 3;
        int a   = rem - gx * 3;
        float aw = (a == 0) ? AW0 : (a == 1) ? AW1 : AW2;
        float ah = (a == 0) ? AH0 : (a == 1) ? AH1 : AH2;

        size_t bn = (size_t)b * Nl + n;
        float so = sigmoidf_(obj[bn]);

        const float4* cv = reinterpret_cast<const float4*>(cls + bn * NUM_CLS);
        float best = -1.0f; int bc = 0;
        #pragma unroll 4
        for (int t = 0; t < NUM_CLS / 4; ++t) {
            float4 v = cv[t];
            float s;
            s = sigmoidf_(v.x); if (s > best) { best = s; bc = 4 * t + 0; }
            s = sigmoidf_(v.y); if (s > best) { best = s; bc = 4 * t + 1; }
            s = sigmoidf_(v.z); if (s > best) { best = s; bc = 4 * t + 2; }
            s = sigmoidf_(v.w); if (s > best) { best = s; bc = 4 * t + 3; }
        }
        float score = best * so;

        float4 rv = reinterpret_cast<const float4*>(reg)[bn];
        float cx = (sigmoidf_(rv.x) + (float)gx) * stf;
        float cy = (sigmoidf_(rv.y) + (float)gy) * stf;
        float w  = expf(rv.z) * aw;
        float h  = expf(rv.w) * ah;
        float x1f = cx - 0.5f * w;
        float y1f = cy - 0.5f * h;
        float x2f = w + x1f;
        float y2f = h + y1f;
        int x1 = (int)x1f, y1 = (int)y1f, x2 = (int)x2f, y2 = (int)y2f;
        x1 = (x1 < 0) ? 0 : x1;
        y1 = (y1 < 0) ? 0 : y1;
        x2 = (x2 > IMG_MAX) ? IMG_MAX : x2;
        y2 = (y2 > IMG_MAX) ? IMG_MAX : y2;

        size_t gI = (size_t)b * NTOT + na;
        // key = raw score bits << 15 | (Nl-n): strict total order == top_k order
        A.decKey[gI] = ((unsigned long long)__float_as_uint(score) << 15) | (unsigned)(Nl - n);
        A.decC[gI] = (float)bc;
        reinterpret_cast<float4*>(A.decB)[gI] =
            make_float4((float)x1, (float)y1, (float)x2, (float)y2);
    }
    grid.sync();

    // ================= Phase B: exact per-level top-1000, sorted ==========
    if (blockIdx.x < BATCH * 3) {
        int b   = blockIdx.x / 3;
        int lvl = blockIdx.x % 3;
        int off = (lvl == 0) ? 0 : (lvl == 1) ? OFF1 : OFF2;
        int Nl  = (lvl == 0) ? N0 : (lvl == 1) ? N1 : N2;

        const unsigned long long* keys = A.decKey + (size_t)b * NTOT + off;

        for (int t = tid; t < NBIN; t += BLK) sm.sel.hist[t] = 0;
        if (tid == 0) { sm.sel.sTot = 0; sm.sel.sOvf = 0; }
        __syncthreads();

        for (int t = tid; t < Nl; t += BLK)
            atomicAdd(&sm.sel.hist[(unsigned)(keys[t] >> 33)], 1u);
        __syncthreads();

        if (tid < NBIN / 64) {
            unsigned s = 0;
            for (int j = 0; j < 64; ++j) s += sm.sel.hist[tid * 64 + j];
            sm.sel.chunkH[tid] = s;
        }
        __syncthreads();
        if (tid == 0) {
            unsigned run = 0;
            for (int c = NBIN / 64 - 1; c >= 0; --c) {
                unsigned t = sm.sel.chunkH[c]; sm.sel.chunkH[c] = run; run += t;
            }
        }
        __syncthreads();
        if (tid < NBIN / 64) {
            unsigned run = sm.sel.chunkH[tid];
            for (int q = 63; q >= 0; --q) {
                sm.sel.cum[tid * 64 + q] = run;
                run += sm.sel.hist[tid * 64 + q];
            }
        }
        __syncthreads();

        for (int t = tid; t < NBIN; t += BLK) sm.sel.hist[t] = 0; // cursor/cnt
        __syncthreads();

        for (int t = tid; t < Nl; t += BLK) {
            unsigned long long k = keys[t];
            unsigned bin = (unsigned)(k >> 33);
            if (sm.sel.cum[bin] < (unsigned)TOPN) {
                unsigned c = atomicAdd(&sm.sel.hist[bin], 1u);
                unsigned p = sm.sel.cum[bin] + c;
                atomicAdd(&sm.sel.sTot, 1);
                if (p < STCAP) { sm.sel.stKey[p] = k; sm.sel.stIdx[p] = t; }
                else sm.sel.sOvf = 1;
            }
        }
        __syncthreads();

        auto writeOut = [&](int t, int r) {
            size_t g = (size_t)b * NTOT + off + t;
            unsigned long long k = keys[t];
            float sraw = __uint_as_float((unsigned)(k >> 15));
            int G = off + t;
            // raw-score global key: order among score<=0.05 entries differs
            // from ref but is provably irrelevant (never keep/suppress/output).
            unsigned long long gk =
                ((unsigned long long)(__float_as_uint(sraw) | 0x80000000u) << 16) |
                (unsigned)(NTOT - G);
            int o = b * NSEL + lvl * TOPN + r;
            A.selC[o] = A.decC[g];
            A.selKey[o] = gk;
            reinterpret_cast<float4*>(A.selB)[o] =
                reinterpret_cast<const float4*>(A.decB)[g];
        };

        if (sm.sel.sOvf == 0) {
            int M = sm.sel.sTot;
            for (int p = tid; p < M; p += BLK) {
                unsigned long long k = sm.sel.stKey[p];
                unsigned bin = (unsigned)(k >> 33);
                unsigned start = sm.sel.cum[bin], end = start + sm.sel.hist[bin];
                int r = (int)start;
                for (unsigned q = start; q < end; ++q)
                    r += (sm.sel.stKey[q] > k) ? 1 : 0;
                if (r < TOPN) writeOut(sm.sel.stIdx[p], r);
            }
        } else {
            // -------- never-expected exact fallback --------
            if (tid == 0) {
                A.gflagImg[b] = 1;
                int B = 0;
                for (int bin = NBIN - 1; bin >= 0; --bin) {
                    if (sm.sel.cum[bin] <= (unsigned)(TOPN - 1) &&
                        sm.sel.cum[bin] + sm.sel.hist[bin] > (unsigned)(TOPN - 1)) {
                        B = bin; break;
                    }
                }
                sm.sel.sBstar = B; sm.sel.sNeed = TOPN - (int)sm.sel.cum[B];
            }
            __syncthreads();
            int Bstar = sm.sel.sBstar, need = sm.sel.sNeed;
            for (int t = tid; t < Nl; t += BLK) {
                unsigned long long k = keys[t];
                int bin = (int)(unsigned)(k >> 33);
                bool em = false;
                if (bin > Bstar) em = true;
                else if (bin == Bstar) {
                    int r = 0;
                    for (int j = 0; j < Nl; ++j) {
                        unsigned long long kj = keys[j];
                        r += ((int)(unsigned)(kj >> 33) == Bstar && kj > k) ? 1 : 0;
                    }
                    em = (r < need);
                }
                if (em) {
                    int r = atomicAdd(&A.fbCursor[b * 3 + lvl], 1);
                    writeOut(t, r);
                }
            }
        }
    }
    grid.sync();

    // ================= Phase C: merge 3 sorted lists ======================
    if (blockIdx.x < BATCH * 3) {
        int b   = blockIdx.x / 3;
        int lvl = blockIdx.x % 3;
        for (int t = tid; t < NSEL; t += BLK) sm.mrg.ks[t] = A.selKey[b * NSEL + t];
        __syncthreads();
        int fb = A.gflagImg[b];

        for (int q = tid; q < TOPN; q += BLK) {
            int t = lvl * TOPN + q;
            unsigned long long k = sm.mrg.ks[t];
            int rank;
            if (!fb) {
                rank = q;
                #pragma unroll
                for (int m = 0; m < 3; ++m) {
                    if (m == lvl) continue;
                    int base = m * TOPN, lo = 0, hi = TOPN;
                    while (lo < hi) {
                        int mid = (lo + hi) >> 1;
                        if (sm.mrg.ks[base + mid] > k) lo = mid + 1; else hi = mid;
                    }
                    rank += lo;
                }
            } else {
                int r = 0;
                for (int j = 0; j < NSEL; ++j) r += (sm.mrg.ks[j] > k) ? 1 : 0;
                rank = r;
            }
            float s = __uint_as_float((unsigned)(k >> 16) & 0x7fffffffu);
            int o = b * NSEL + rank;
            A.srtS[o] = (s > MIN_SCORE_F) ? s : -1.0f;
            A.srtC[o] = A.selC[b * NSEL + t];
            reinterpret_cast<float4*>(A.srtB)[o] =
                reinterpret_cast<const float4*>(A.selB)[b * NSEL + t];
        }
    }
    grid.sync();

    // ================= Phase D: pairwise suppression masks ================
    // One wave per 64x64 upper-triangle tile; lane owns column box j, row
    // boxes preloaded coalesced + shfl-broadcast. gmask column-major [b][w][i].
    {
        int lane = tid & 63;
        int wid  = gtid >> 6;
        for (int task = wid; task < BATCH * NTASK; task += NWAVE) {
            int b = task / NTASK;
            int u = task % NTASK;
            int r = 0;
            while (u >= WPR - r) { u -= WPR - r; r++; }
            int w = r + u;

            int jIdx = w * 64 + lane;
            const float4* Bx = reinterpret_cast<const float4*>(A.srtB) + (size_t)b * NSEL;

            float4 nobox = make_float4(4e8f, 4e8f, -4e8f, -4e8f);
            float4 bj = (jIdx < NSEL) ? Bx[jIdx] : nobox;
            float aj = (bj.z - bj.x) * (bj.w - bj.y);

            int rowBase = r * 64;
            int rIdx = rowBase + lane;
            float4 rowbox = (rIdx < NSEL) ? Bx[rIdx] : nobox;

            unsigned long long rowWord = 0ull;
            #pragma unroll 8
            for (int it = 0; it < 64; ++it) {
                float4 bi;
                bi.x = __shfl(rowbox.x, it);
                bi.y = __shfl(rowbox.y, it);
                bi.z = __shfl(rowbox.z, it);
                bi.w = __shfl(rowbox.w, it);
                float ai = (bi.z - bi.x) * (bi.w - bi.y);
                float xx1 = fmaxf(bi.x, bj.x);
                float yy1 = fmaxf(bi.y, bj.y);
                float xx2 = fminf(bi.z, bj.z);
                float yy2 = fminf(bi.w, bj.w);
                float inter = fmaxf(xx2 - xx1, 0.0f) * fmaxf(yy2 - yy1, 0.0f);
                float uni = ai + aj - inter;
                // exact vs iou>0.5: inter/uni exact ints < 2^20 in fp32
                bool sup = (inter > 0.5f * uni) && (inter > 0.0f) && (jIdx > rowBase + it);
                unsigned long long word = __ballot(sup);
                if (lane == it) rowWord = word;
            }
            if (rIdx < NSEL)
                A.gmask[((size_t)b * WPR + w) * NSEL + rIdx] = rowWord;
        }
    }
    grid.sync();

    // ================= Phase E: greedy resolve + output ===================
    if (blockIdx.x < BATCH) {
        int b = blockIdx.x;
        const unsigned long long* gm = A.gmask + (size_t)b * WPR * NSEL;
        const float* S = A.srtS + b * NSEL;

        for (int k = 0; k < 6; ++k) {
            int j = k * BLK + tid;
            float s = (j < NSEL) ? S[j] : -1.0f;
            unsigned long long bal = __ballot(s > MIN_SCORE_F);
            int wIdx = k * (BLK / 64) + (tid >> 6);
            if ((tid & 63) == 0 && wIdx < WPR) sm.res.validLds[wIdx] = bal;
        }
        __syncthreads();

        if (tid < 64) {
            int lane = tid;
            unsigned long long validw = (lane < WPR) ? sm.res.validLds[lane] : 0ull;
            unsigned long long removed = 0ull;
            int pos = 0;
            bool done = false;
            while (!done) {
                unsigned long long tmp = validw & ~removed;
                int c[WIN];
                int nc = 0;
                #pragma unroll
                for (int k = 0; k < WIN; ++k) {
                    unsigned long long bal = __ballot(tmp != 0ull);
                    if (bal == 0ull) break;            // uniform
                    int fw = __ffsll(bal) - 1;
                    unsigned long long wb = __shfl(tmp, fw);
                    int bit = __ffsll(wb) - 1;
                    c[k] = fw * 64 + bit;
                    nc = k + 1;
                    if (lane == fw) tmp &= tmp - 1ull;
                }
                if (nc == 0) break;

                unsigned long long mk[WIN];
                #pragma unroll
                for (int k = 0; k < WIN; ++k) {
                    mk[k] = 0ull;
                    if (k < nc && lane < WPR && lane >= (c[k] >> 6))
                        mk[k] = gm[(size_t)lane * NSEL + c[k]];
                }

                #pragma unroll
                for (int k = 0; k < WIN; ++k) {
                    if (k >= nc) break;
                    int ck = c[k];
                    unsigned long long availw = __shfl(validw & ~removed, ck >> 6);
                    if ((availw >> (ck & 63)) & 1ull) {   // uniform
                        if (lane == 0) sm.res.keptIdx[pos] = ck;
                        pos++;
                        if (lane == (ck >> 6)) validw &= ~(1ull << (ck & 63));
                        removed |= mk[k];
                        if (pos >= MAXDET) { done = true; break; }
                    }
                }
            }
            if (lane == 0) sm.res.sPos = pos;
        }
        __syncthreads();

        int pos = sm.res.sPos;
        const float*  C  = A.srtC + b * NSEL;
        const float4* Bx = reinterpret_cast<const float4*>(A.srtB) + (size_t)b * NSEL;
        float* out_s = A.out + b * MAXDET;
        float* out_c = A.out + BATCH * MAXDET + b * MAXDET;
        float* out_b = A.out + 2 * BATCH * MAXDET + (size_t)b * MAXDET * 4;
        for (int t = tid; t < MAXDET; t += BLK) {
            if (t < pos) {
                int ki = sm.res.keptIdx[t];
                float4 bb = Bx[ki];
                out_s[t] = S[ki];
                out_c[t] = C[ki];
                out_b[t * 4 + 0] = bb.x; out_b[t * 4 + 1] = bb.y;
                out_b[t * 4 + 2] = bb.z; out_b[t * 4 + 3] = bb.w;
            } else {
                out_s[t] = -1.0f; out_c[t] = -1.0f;
                out_b[t * 4 + 0] = -1.0f; out_b[t * 4 + 1] = -1.0f;
                out_b[t * 4 + 2] = -1.0f; out_b[t * 4 + 3] = -1.0f;
            }
        }
    }
}

// ---------------- host launcher ----------------
extern "C" void kernel_launch(void* const* d_in, const int* in_sizes, int n_in,
                              void* d_out, int out_size, void* d_ws, size_t ws_size,
                              hipStream_t stream) {
    (void)n_in; (void)out_size; (void)ws_size;

    bool dict = (in_sizes[2] == BATCH * N0 * NUM_CLS); // 693120
    const float *obj[3], *reg[3], *cls[3];
    for (int l = 0; l < 3; ++l) {
        obj[l] = (const float*)d_in[dict ? 4 * l + 0 : l];
        reg[l] = (const float*)d_in[dict ? 4 * l + 1 : 3 + l];
        cls[l] = (const float*)d_in[dict ? 4 * l + 2 : 6 + l];
    }

    char* ws = (char*)d_ws;
    size_t off = 0;
    auto take = [&](size_t bytes) -> void* {
        void* p = ws + off;
        off += (bytes + 255) & ~(size_t)255;
        return p;
    };
    MegaArgs A;
    A.obj0 = obj[0]; A.reg0 = reg[0]; A.cls0 = cls[0];
    A.obj1 = obj[1]; A.reg1 = reg[1]; A.cls1 = cls[1];
    A.obj2 = obj[2]; A.reg2 = reg[2]; A.cls2 = cls[2];
    A.gflagImg = (int*)take(BATCH * sizeof(int));
    A.fbCursor = (int*)take(BATCH * 3 * sizeof(int));
    A.decKey   = (unsigned long long*)take((size_t)BATCH * NTOT * 8);
    A.decC     = (float*)take((size_t)BATCH * NTOT * 4);
    A.decB     = (float*)take((size_t)BATCH * NTOT * 16);
    A.selC     = (float*)take((size_t)BATCH * NSEL * 4);
    A.selB     = (float*)take((size_t)BATCH * NSEL * 16);
    A.selKey   = (unsigned long long*)take((size_t)BATCH * NSEL * 8);
    A.srtS     = (float*)take((size_t)BATCH * NSEL * 4);
    A.srtC     = (float*)take((size_t)BATCH * NSEL * 4);
    A.srtB     = (float*)take((size_t)BATCH * NSEL * 16);
    A.gmask    = (unsigned long long*)take((size_t)BATCH * WPR * NSEL * 8 + 256);
    A.out      = (float*)d_out;

    void* params[] = { &A };
    hipLaunchCooperativeKernel(reinterpret_cast<void*>(k_mega),
                               dim3(GRID), dim3(BLK), params, 0, stream);
}

// Round 8
// 228.372 us; speedup vs baseline: 1.6284x; 1.6284x over previous
//
#include <hip/hip_runtime.h>
#include <math.h>

// ---------------- problem constants ----------------
constexpr int BATCH   = 8;
constexpr int NUM_CLS = 80;
constexpr int N0 = 19 * 19 * 3;   // 1083  (stride 32)
constexpr int N1 = 38 * 38 * 3;   // 4332  (stride 16)
constexpr int N2 = 76 * 76 * 3;   // 17328 (stride 8)
constexpr int OFF1 = N0;          // 1083
constexpr int OFF2 = N0 + N1;     // 5415
constexpr int NTOT = N0 + N1 + N2; // 22743 per image
constexpr int TOPN = 1000;
constexpr int NSEL = 3 * TOPN;    // 3000 per image
constexpr int MAXDET = 100;
constexpr float MIN_SCORE_F = 0.05f;
constexpr int IMG_MAX = 607;
constexpr int WPR = (NSEL + 63) / 64; // 47 u64 words per mask row

__device__ __forceinline__ float sigmoidf_(float x) {
    return 1.0f / (1.0f + expf(-x));
}

// ---------------- K1: decode all candidates (analytic anchors) ---------------
// anchors = (gx, gy, AW*st, AH*st, st) with st a power of 2, so
// exp(r)*(AW*st)/st == exp(r)*AW bit-exactly, and (sig+gx)*st is unchanged.
__global__ __launch_bounds__(256) void k_decode(
    const float* __restrict__ obj0, const float* __restrict__ reg0,
    const float* __restrict__ cls0,
    const float* __restrict__ obj1, const float* __restrict__ reg1,
    const float* __restrict__ cls1,
    const float* __restrict__ obj2, const float* __restrict__ reg2,
    const float* __restrict__ cls2,
    unsigned long long* __restrict__ decKey, float* __restrict__ decC,
    float* __restrict__ decB, int* __restrict__ gflagImg, int* __restrict__ fbCursor)
{
    if (blockIdx.x == 0 && threadIdx.x < 32) {
        if (threadIdx.x < 8)  gflagImg[threadIdx.x] = 0;
        if (threadIdx.x < 24) fbCursor[threadIdx.x] = 0;
    }
    int idx = blockIdx.x * 256 + threadIdx.x;
    if (idx >= BATCH * NTOT) return;
    int b  = idx / NTOT;
    int na = idx - b * NTOT;

    const float *obj, *reg, *cls;
    int Nl, n, g;
    float stf, AW0, AW1, AW2, AH0, AH1, AH2;
    if (na < OFF1) {
        obj = obj0; reg = reg0; cls = cls0; Nl = N0; n = na; g = 19; stf = 32.f;
        AW0 = 116.f; AW1 = 156.f; AW2 = 373.f; AH0 = 90.f; AH1 = 198.f; AH2 = 326.f;
    } else if (na < OFF2) {
        obj = obj1; reg = reg1; cls = cls1; Nl = N1; n = na - OFF1; g = 38; stf = 16.f;
        AW0 = 30.f; AW1 = 62.f; AW2 = 59.f; AH0 = 61.f; AH1 = 45.f; AH2 = 119.f;
    } else {
        obj = obj2; reg = reg2; cls = cls2; Nl = N2; n = na - OFF2; g = 76; stf = 8.f;
        AW0 = 10.f; AW1 = 16.f; AW2 = 33.f; AH0 = 13.f; AH1 = 30.f; AH2 = 23.f;
    }
    int g3  = g * 3;
    int gy  = n / g3;
    int rem = n - gy * g3;
    int gx  = rem / 3;
    int a   = rem - gx * 3;
    float aw = (a == 0) ? AW0 : (a == 1) ? AW1 : AW2;
    float ah = (a == 0) ? AH0 : (a == 1) ? AH1 : AH2;

    size_t bn = (size_t)b * Nl + n;

    float so = sigmoidf_(obj[bn]);

    const float4* cv = reinterpret_cast<const float4*>(cls + bn * NUM_CLS);
    float best = -1.0f; int bc = 0;
    #pragma unroll 4
    for (int t = 0; t < NUM_CLS / 4; ++t) {
        float4 v = cv[t];
        float s;
        s = sigmoidf_(v.x); if (s > best) { best = s; bc = 4 * t + 0; }
        s = sigmoidf_(v.y); if (s > best) { best = s; bc = 4 * t + 1; }
        s = sigmoidf_(v.z); if (s > best) { best = s; bc = 4 * t + 2; }
        s = sigmoidf_(v.w); if (s > best) { best = s; bc = 4 * t + 3; }
    }
    float score = best * so;

    float4 rv = reinterpret_cast<const float4*>(reg)[bn];
    float cx = (sigmoidf_(rv.x) + (float)gx) * stf;
    float cy = (sigmoidf_(rv.y) + (float)gy) * stf;
    float w  = expf(rv.z) * aw;
    float h  = expf(rv.w) * ah;
    float x1f = cx - 0.5f * w;
    float y1f = cy - 0.5f * h;
    float x2f = w + x1f;
    float y2f = h + y1f;
    int x1 = (int)x1f, y1 = (int)y1f, x2 = (int)x2f, y2 = (int)y2f;
    x1 = (x1 < 0) ? 0 : x1;
    y1 = (y1 < 0) ? 0 : y1;
    x2 = (x2 > IMG_MAX) ? IMG_MAX : x2;
    y2 = (y2 > IMG_MAX) ? IMG_MAX : y2;

    size_t gidx = (size_t)b * NTOT + na;
    // key = raw score bits << 15 | (Nl - n): strict total order == top_k order
    decKey[gidx] = ((unsigned long long)__float_as_uint(score) << 15) | (unsigned)(Nl - n);
    decC[gidx] = (float)bc;
    reinterpret_cast<float4*>(decB)[gidx] =
        make_float4((float)x1, (float)y1, (float)x2, (float)y2);
}

// ---------------- K2: exact per-level top-1000, PLACED IN SORTED ORDER -------
constexpr int NBIN  = 4096;
constexpr int STCAP = 2048;

__global__ __launch_bounds__(1024) void k_select(
    const unsigned long long* __restrict__ decKey, const float* __restrict__ decC,
    const float* __restrict__ decB, float* __restrict__ selC,
    float* __restrict__ selB, unsigned long long* __restrict__ selKey,
    int* __restrict__ gflagImg, int* __restrict__ fbCursor)
{
    __shared__ unsigned hist[NBIN];            // counts, then per-bucket cursor/cnt
    __shared__ unsigned cum[NBIN];             // strictly-higher counts
    __shared__ unsigned chunkH[NBIN / 64];     // 64
    __shared__ unsigned long long stKey[STCAP];
    __shared__ int stIdx[STCAP];
    __shared__ int sTot; __shared__ int sOvf;
    __shared__ int sBstar; __shared__ int sNeed;

    int b   = blockIdx.x / 3;
    int lvl = blockIdx.x % 3;
    int off = (lvl == 0) ? 0 : (lvl == 1) ? OFF1 : OFF2;
    int Nl  = (lvl == 0) ? N0 : (lvl == 1) ? N1 : N2;
    int tid = threadIdx.x;

    const unsigned long long* keys = decKey + (size_t)b * NTOT + off;

    for (int t = tid; t < NBIN; t += 1024) hist[t] = 0;
    if (tid == 0) { sTot = 0; sOvf = 0; }
    __syncthreads();

    for (int t = tid; t < Nl; t += 1024)
        atomicAdd(&hist[(unsigned)(keys[t] >> 33)], 1u);
    __syncthreads();

    if (tid < NBIN / 64) {
        unsigned s = 0;
        for (int j = 0; j < 64; ++j) s += hist[tid * 64 + j];
        chunkH[tid] = s;
    }
    __syncthreads();
    if (tid == 0) {
        unsigned run = 0;
        for (int c = NBIN / 64 - 1; c >= 0; --c) {
            unsigned t = chunkH[c]; chunkH[c] = run; run += t;
        }
    }
    __syncthreads();
    if (tid < NBIN / 64) {
        unsigned run = chunkH[tid];
        for (int q = 63; q >= 0; --q) {
            cum[tid * 64 + q] = run;
            run += hist[tid * 64 + q];
        }
    }
    __syncthreads();

    for (int t = tid; t < NBIN; t += 1024) hist[t] = 0; // becomes cursor/cnt
    __syncthreads();

    for (int t = tid; t < Nl; t += 1024) {
        unsigned long long k = keys[t];
        unsigned bin = (unsigned)(k >> 33);
        if (cum[bin] < (unsigned)TOPN) {
            unsigned c = atomicAdd(&hist[bin], 1u);
            unsigned p = cum[bin] + c;
            atomicAdd(&sTot, 1);
            if (p < STCAP) { stKey[p] = k; stIdx[p] = t; }
            else sOvf = 1;
        }
    }
    __syncthreads();

    auto writeOut = [&](int t, int r) {
        size_t g = (size_t)b * NTOT + off + t;
        unsigned long long k = keys[t];
        float sraw = __uint_as_float((unsigned)(k >> 15));
        int G = off + t;
        // raw-score global key: order among score<=0.05 entries differs from ref
        // but is provably irrelevant (they never keep/suppress/output).
        unsigned long long gk =
            ((unsigned long long)(__float_as_uint(sraw) | 0x80000000u) << 16) |
            (unsigned)(NTOT - G);
        int o = b * NSEL + lvl * TOPN + r;
        selC[o] = decC[g];
        selKey[o] = gk;
        reinterpret_cast<float4*>(selB)[o] = reinterpret_cast<const float4*>(decB)[g];
    };

    if (sOvf == 0) {
        int M = sTot;
        for (int p = tid; p < M; p += 1024) {
            unsigned long long k = stKey[p];
            unsigned bin = (unsigned)(k >> 33);
            unsigned start = cum[bin], end = start + hist[bin];
            int r = (int)start;
            for (unsigned q = start; q < end; ++q) r += (stKey[q] > k) ? 1 : 0;
            if (r < TOPN) writeOut(stIdx[p], r);
        }
    } else {
        // -------- never-expected exact fallback --------
        if (tid == 0) {
            gflagImg[b] = 1;
            int B = 0;
            for (int bin = NBIN - 1; bin >= 0; --bin) {
                if (cum[bin] <= (unsigned)(TOPN - 1) &&
                    cum[bin] + hist[bin] > (unsigned)(TOPN - 1)) { B = bin; break; }
            }
            sBstar = B; sNeed = TOPN - (int)cum[B];
        }
        __syncthreads();
        int Bstar = sBstar, need = sNeed;
        for (int t = tid; t < Nl; t += 1024) {
            unsigned long long k = keys[t];
            int bin = (int)(unsigned)(k >> 33);
            bool em = false;
            if (bin > Bstar) em = true;
            else if (bin == Bstar) {
                int r = 0;
                for (int j = 0; j < Nl; ++j) {
                    unsigned long long kj = keys[j];
                    r += ((int)(unsigned)(kj >> 33) == Bstar && kj > k) ? 1 : 0;
                }
                em = (r < need);
            }
            if (em) {
                int r = atomicAdd(&fbCursor[b * 3 + lvl], 1);
                writeOut(t, r);
            }
        }
    }
}

// ---------------- K3: merge 3 sorted lists -> global sorted order ------------
// 24 blocks: block = (image, level); each ranks its level's 1000 entries.
__global__ __launch_bounds__(256) void k_merge(
    const float* __restrict__ selC, const float* __restrict__ selB,
    const unsigned long long* __restrict__ selKey, const int* __restrict__ gflagImg,
    float* __restrict__ srtS, float* __restrict__ srtC, float* __restrict__ srtB)
{
    __shared__ unsigned long long ks[NSEL]; // 24 KB
    int b   = blockIdx.x / 3;
    int lvl = blockIdx.x % 3;
    int tid = threadIdx.x;
    for (int t = tid; t < NSEL; t += 256) ks[t] = selKey[b * NSEL + t];
    __syncthreads();
    int fb = gflagImg[b];

    for (int q = tid; q < TOPN; q += 256) {
        int t = lvl * TOPN + q;
        unsigned long long k = ks[t];
        int rank;
        if (!fb) {
            rank = q;
            #pragma unroll
            for (int m = 0; m < 3; ++m) {
                if (m == lvl) continue;
                int base = m * TOPN, lo = 0, hi = TOPN;
                while (lo < hi) {
                    int mid = (lo + hi) >> 1;
                    if (ks[base + mid] > k) lo = mid + 1; else hi = mid;
                }
                rank += lo;
            }
        } else {
            int r = 0;
            for (int j = 0; j < NSEL; ++j) r += (ks[j] > k) ? 1 : 0;
            rank = r;
        }
        // transformed score from key: raw = (gk>>16) & 0x7fffffff (scores >= 0)
        float s = __uint_as_float((unsigned)(k >> 16) & 0x7fffffffu);
        int o = b * NSEL + rank;
        srtS[o] = (s > MIN_SCORE_F) ? s : -1.0f;
        srtC[o] = selC[b * NSEL + t];
        reinterpret_cast<float4*>(srtB)[o] =
            reinterpret_cast<const float4*>(selB)[b * NSEL + t];
    }
}

// ---------------- K4a: pairwise suppression masks, register/ballot ----------
// One wave per 64x64 upper-triangle tile. Lane owns column box j in registers;
// row boxes are pre-loaded coalesced (one float4 per lane) and broadcast per
// iteration via 4 shfls (no per-row VMEM). gmask is column-major [b][w][i] ->
// coalesced stores. Sub-diagonal words (w < i>>6) are NOT written; k_resolve
// zeroes them at use.
constexpr int NTASK = WPR * (WPR + 1) / 2; // 1128 per image

__global__ __launch_bounds__(256) void k_iou(
    const float* __restrict__ srtB, unsigned long long* __restrict__ gmask)
{
    int wtask = blockIdx.x * 4 + (threadIdx.x >> 6);
    if (wtask >= BATCH * NTASK) return;
    int b = wtask / NTASK;
    int u = wtask % NTASK;
    int r = 0;
    while (u >= WPR - r) { u -= WPR - r; r++; }
    int w = r + u;

    int lane = threadIdx.x & 63;
    int jIdx = w * 64 + lane;
    const float4* Bx = reinterpret_cast<const float4*>(srtB) + (size_t)b * NSEL;

    float4 nobox = make_float4(4e8f, 4e8f, -4e8f, -4e8f); // never intersects
    float4 bj = (jIdx < NSEL) ? Bx[jIdx] : nobox;
    float aj = (bj.z - bj.x) * (bj.w - bj.y);

    int rowBase = r * 64;
    int rIdx = rowBase + lane;
    float4 rowbox = (rIdx < NSEL) ? Bx[rIdx] : nobox;

    unsigned long long rowWord = 0ull;
    #pragma unroll 8
    for (int it = 0; it < 64; ++it) {
        float4 bi;
        bi.x = __shfl(rowbox.x, it);
        bi.y = __shfl(rowbox.y, it);
        bi.z = __shfl(rowbox.z, it);
        bi.w = __shfl(rowbox.w, it);
        float ai = (bi.z - bi.x) * (bi.w - bi.y);
        float xx1 = fmaxf(bi.x, bj.x);
        float yy1 = fmaxf(bi.y, bj.y);
        float xx2 = fminf(bi.z, bj.z);
        float yy2 = fminf(bi.w, bj.w);
        float inter = fmaxf(xx2 - xx1, 0.0f) * fmaxf(yy2 - yy1, 0.0f);
        float uni = ai + aj - inter;
        // exact vs iou>0.5: inter/uni are exact ints < 2^20 in fp32
        bool sup = (inter > 0.5f * uni) && (inter > 0.0f) && (jIdx > rowBase + it);
        unsigned long long word = __ballot(sup);
        if (lane == it) rowWord = word;
    }
    if (rIdx < NSEL)
        gmask[((size_t)b * WPR + w) * NSEL + rIdx] = rowWord;
}

// ---------------- K4b: greedy resolve with batched speculative prefetch ------
// Per round: pick first WIN available candidates from the register bitmap
// (ballot/ffs only), gather all WIN mask rows concurrently (one round trip),
// apply greedily in-window (kept iff avail bit survived rows applied so far).
// Exactly greedy; every window slot is consumed -> guaranteed progress.
constexpr int WIN = 12;

__global__ __launch_bounds__(256) void k_resolve(
    const float* __restrict__ srtS, const float* __restrict__ srtC,
    const float* __restrict__ srtB, const unsigned long long* __restrict__ gmask,
    float* __restrict__ out)
{
    __shared__ unsigned long long validLds[WPR];
    __shared__ int keptIdx[MAXDET];
    __shared__ int sPos;

    int b = blockIdx.x, tid = threadIdx.x;
    const unsigned long long* gm = gmask + (size_t)b * WPR * NSEL;
    const float* S = srtS + b * NSEL;

    // valid bitmap: wave w's ballot at iteration k covers word k*4+w
    for (int k = 0; k < 12; ++k) {
        int j = k * 256 + tid;
        float s = (j < NSEL) ? S[j] : -1.0f;
        unsigned long long bal = __ballot(s > MIN_SCORE_F);
        int wIdx = k * 4 + (tid >> 6);
        if ((tid & 63) == 0 && wIdx < WPR) validLds[wIdx] = bal;
    }
    __syncthreads();

    if (tid < 64) {
        int lane = tid;
        unsigned long long validw = (lane < WPR) ? validLds[lane] : 0ull;
        unsigned long long removed = 0ull;
        int pos = 0;
        bool done = false;
        while (!done) {
            // ---- pick first WIN avail candidates (uniform, register-only) ----
            unsigned long long tmp = validw & ~removed;
            int c[WIN];
            int nc = 0;
            #pragma unroll
            for (int k = 0; k < WIN; ++k) {
                unsigned long long bal = __ballot(tmp != 0ull);
                if (bal == 0ull) break;            // uniform
                int fw = __ffsll(bal) - 1;
                unsigned long long wb = __shfl(tmp, fw);
                int bit = __ffsll(wb) - 1;
                c[k] = fw * 64 + bit;
                nc = k + 1;
                if (lane == fw) tmp &= tmp - 1ull;  // clear lowest set bit
            }
            if (nc == 0) break;

            // ---- concurrent gather of all WIN mask rows (one round trip) ----
            unsigned long long mk[WIN];
            #pragma unroll
            for (int k = 0; k < WIN; ++k) {
                mk[k] = 0ull;
                if (k < nc && lane < WPR && lane >= (c[k] >> 6))
                    mk[k] = gm[(size_t)lane * NSEL + c[k]];
            }

            // ---- greedy apply within window ----
            #pragma unroll
            for (int k = 0; k < WIN; ++k) {
                if (k >= nc) break;
                int ck = c[k];
                unsigned long long availw = __shfl(validw & ~removed, ck >> 6);
                if ((availw >> (ck & 63)) & 1ull) {   // uniform
                    if (lane == 0) keptIdx[pos] = ck;
                    pos++;
                    if (lane == (ck >> 6)) validw &= ~(1ull << (ck & 63));
                    removed |= mk[k];
                    if (pos >= MAXDET) { done = true; break; }
                }
            }
        }
        if (lane == 0) sPos = pos;
    }
    __syncthreads();

    int pos = sPos;
    const float*  C  = srtC + b * NSEL;
    const float4* Bx = reinterpret_cast<const float4*>(srtB) + (size_t)b * NSEL;
    float* out_s = out + b * MAXDET;
    float* out_c = out + BATCH * MAXDET + b * MAXDET;
    float* out_b = out + 2 * BATCH * MAXDET + (size_t)b * MAXDET * 4;
    for (int t = tid; t < MAXDET; t += 256) {
        if (t < pos) {
            int ki = keptIdx[t];
            float4 bb = Bx[ki];
            out_s[t] = S[ki];
            out_c[t] = C[ki];
            out_b[t * 4 + 0] = bb.x; out_b[t * 4 + 1] = bb.y;
            out_b[t * 4 + 2] = bb.z; out_b[t * 4 + 3] = bb.w;
        } else {
            out_s[t] = -1.0f; out_c[t] = -1.0f;
            out_b[t * 4 + 0] = -1.0f; out_b[t * 4 + 1] = -1.0f;
            out_b[t * 4 + 2] = -1.0f; out_b[t * 4 + 3] = -1.0f;
        }
    }
}

// ---------------- host launcher ----------------
extern "C" void kernel_launch(void* const* d_in, const int* in_sizes, int n_in,
                              void* d_out, int out_size, void* d_ws, size_t ws_size,
                              hipStream_t stream) {
    (void)n_in; (void)out_size; (void)ws_size;

    bool dict = (in_sizes[2] == BATCH * N0 * NUM_CLS); // 693120
    const float *obj[3], *reg[3], *cls[3];
    for (int l = 0; l < 3; ++l) {
        obj[l] = (const float*)d_in[dict ? 4 * l + 0 : l];
        reg[l] = (const float*)d_in[dict ? 4 * l + 1 : 3 + l];
        cls[l] = (const float*)d_in[dict ? 4 * l + 2 : 6 + l];
    }

    char* ws = (char*)d_ws;
    size_t off = 0;
    auto take = [&](size_t bytes) -> void* {
        void* p = ws + off;
        off += (bytes + 255) & ~(size_t)255;
        return p;
    };
    int*                 gflagImg = (int*)take(BATCH * sizeof(int));
    int*                 fbCursor = (int*)take(BATCH * 3 * sizeof(int));
    unsigned long long*  decKey   = (unsigned long long*)take((size_t)BATCH * NTOT * 8);
    float*               decC     = (float*)take((size_t)BATCH * NTOT * 4);
    float*               decB     = (float*)take((size_t)BATCH * NTOT * 16);
    float*               selC     = (float*)take((size_t)BATCH * NSEL * 4);
    float*               selB     = (float*)take((size_t)BATCH * NSEL * 16);
    unsigned long long*  selKey   = (unsigned long long*)take((size_t)BATCH * NSEL * 8);
    float*               srtS     = (float*)take((size_t)BATCH * NSEL * 4);
    float*               srtC     = (float*)take((size_t)BATCH * NSEL * 4);
    float*               srtB     = (float*)take((size_t)BATCH * NSEL * 16);
    unsigned long long*  gmask    = (unsigned long long*)take((size_t)BATCH * WPR * NSEL * 8 + 256);

    int totalDec = BATCH * NTOT; // 181944
    k_decode<<<(totalDec + 255) / 256, 256, 0, stream>>>(
        obj[0], reg[0], cls[0],
        obj[1], reg[1], cls[1],
        obj[2], reg[2], cls[2],
        decKey, decC, decB, gflagImg, fbCursor);

    k_select<<<BATCH * 3, 1024, 0, stream>>>(decKey, decC, decB,
                                             selC, selB, selKey,
                                             gflagImg, fbCursor);

    k_merge<<<BATCH * 3, 256, 0, stream>>>(selC, selB, selKey, gflagImg,
                                           srtS, srtC, srtB);

    int nIouBlocks = (BATCH * NTASK + 3) / 4; // 2256
    k_iou<<<nIouBlocks, 256, 0, stream>>>(srtB, gmask);

    k_resolve<<<BATCH, 256, 0, stream>>>(srtS, srtC, srtB, gmask, (float*)d_out);
}

// Round 9
// 216.403 us; speedup vs baseline: 1.7184x; 1.0553x over previous
//
#include <hip/hip_runtime.h>
#include <math.h>

// ---------------- problem constants ----------------
constexpr int BATCH   = 8;
constexpr int NUM_CLS = 80;
constexpr int N0 = 19 * 19 * 3;   // 1083  (stride 32)
constexpr int N1 = 38 * 38 * 3;   // 4332  (stride 16)
constexpr int N2 = 76 * 76 * 3;   // 17328 (stride 8)
constexpr int OFF1 = N0;          // 1083
constexpr int OFF2 = N0 + N1;     // 5415
constexpr int NTOT = N0 + N1 + N2; // 22743 per image
constexpr int TOPN = 1000;
constexpr int NSEL = 3 * TOPN;    // 3000 per image
constexpr int MAXDET = 100;
constexpr float MIN_SCORE_F = 0.05f;
constexpr int IMG_MAX = 607;
constexpr int WPR = (NSEL + 63) / 64; // 47 u64 words per mask row
constexpr int RPW = 48;               // padded row width (384 B = 6 cache lines)

__device__ __forceinline__ float sigmoidf_(float x) {
    return 1.0f / (1.0f + expf(-x));
}

// ---------------- K1: decode all candidates (analytic anchors) ---------------
// anchors = (gx, gy, AW*st, AH*st, st) with st a power of 2, so
// exp(r)*(AW*st)/st == exp(r)*AW bit-exactly, and (sig+gx)*st is unchanged.
__global__ __launch_bounds__(256) void k_decode(
    const float* __restrict__ obj0, const float* __restrict__ reg0,
    const float* __restrict__ cls0,
    const float* __restrict__ obj1, const float* __restrict__ reg1,
    const float* __restrict__ cls1,
    const float* __restrict__ obj2, const float* __restrict__ reg2,
    const float* __restrict__ cls2,
    unsigned long long* __restrict__ decKey, float* __restrict__ decC,
    float* __restrict__ decB, int* __restrict__ gflagImg, int* __restrict__ fbCursor)
{
    if (blockIdx.x == 0 && threadIdx.x < 32) {
        if (threadIdx.x < 8)  gflagImg[threadIdx.x] = 0;
        if (threadIdx.x < 24) fbCursor[threadIdx.x] = 0;
    }
    int idx = blockIdx.x * 256 + threadIdx.x;
    if (idx >= BATCH * NTOT) return;
    int b  = idx / NTOT;
    int na = idx - b * NTOT;

    const float *obj, *reg, *cls;
    int Nl, n, g;
    float stf, AW0, AW1, AW2, AH0, AH1, AH2;
    if (na < OFF1) {
        obj = obj0; reg = reg0; cls = cls0; Nl = N0; n = na; g = 19; stf = 32.f;
        AW0 = 116.f; AW1 = 156.f; AW2 = 373.f; AH0 = 90.f; AH1 = 198.f; AH2 = 326.f;
    } else if (na < OFF2) {
        obj = obj1; reg = reg1; cls = cls1; Nl = N1; n = na - OFF1; g = 38; stf = 16.f;
        AW0 = 30.f; AW1 = 62.f; AW2 = 59.f; AH0 = 61.f; AH1 = 45.f; AH2 = 119.f;
    } else {
        obj = obj2; reg = reg2; cls = cls2; Nl = N2; n = na - OFF2; g = 76; stf = 8.f;
        AW0 = 10.f; AW1 = 16.f; AW2 = 33.f; AH0 = 13.f; AH1 = 30.f; AH2 = 23.f;
    }
    int g3  = g * 3;
    int gy  = n / g3;
    int rem = n - gy * g3;
    int gx  = rem / 3;
    int a   = rem - gx * 3;
    float aw = (a == 0) ? AW0 : (a == 1) ? AW1 : AW2;
    float ah = (a == 0) ? AH0 : (a == 1) ? AH1 : AH2;

    size_t bn = (size_t)b * Nl + n;

    float so = sigmoidf_(obj[bn]);

    const float4* cv = reinterpret_cast<const float4*>(cls + bn * NUM_CLS);
    float best = -1.0f; int bc = 0;
    #pragma unroll 4
    for (int t = 0; t < NUM_CLS / 4; ++t) {
        float4 v = cv[t];
        float s;
        s = sigmoidf_(v.x); if (s > best) { best = s; bc = 4 * t + 0; }
        s = sigmoidf_(v.y); if (s > best) { best = s; bc = 4 * t + 1; }
        s = sigmoidf_(v.z); if (s > best) { best = s; bc = 4 * t + 2; }
        s = sigmoidf_(v.w); if (s > best) { best = s; bc = 4 * t + 3; }
    }
    float score = best * so;

    float4 rv = reinterpret_cast<const float4*>(reg)[bn];
    float cx = (sigmoidf_(rv.x) + (float)gx) * stf;
    float cy = (sigmoidf_(rv.y) + (float)gy) * stf;
    float w  = expf(rv.z) * aw;
    float h  = expf(rv.w) * ah;
    float x1f = cx - 0.5f * w;
    float y1f = cy - 0.5f * h;
    float x2f = w + x1f;
    float y2f = h + y1f;
    int x1 = (int)x1f, y1 = (int)y1f, x2 = (int)x2f, y2 = (int)y2f;
    x1 = (x1 < 0) ? 0 : x1;
    y1 = (y1 < 0) ? 0 : y1;
    x2 = (x2 > IMG_MAX) ? IMG_MAX : x2;
    y2 = (y2 > IMG_MAX) ? IMG_MAX : y2;

    size_t gidx = (size_t)b * NTOT + na;
    // key = raw score bits << 15 | (Nl - n): strict total order == top_k order
    decKey[gidx] = ((unsigned long long)__float_as_uint(score) << 15) | (unsigned)(Nl - n);
    decC[gidx] = (float)bc;
    reinterpret_cast<float4*>(decB)[gidx] =
        make_float4((float)x1, (float)y1, (float)x2, (float)y2);
}

// ---------------- K2: exact per-level top-1000, PLACED IN SORTED ORDER -------
constexpr int NBIN  = 4096;
constexpr int STCAP = 2048;

__global__ __launch_bounds__(1024) void k_select(
    const unsigned long long* __restrict__ decKey, const float* __restrict__ decC,
    const float* __restrict__ decB, float* __restrict__ selC,
    float* __restrict__ selB, unsigned long long* __restrict__ selKey,
    int* __restrict__ gflagImg, int* __restrict__ fbCursor)
{
    __shared__ unsigned hist[NBIN];            // counts, then per-bucket cursor/cnt
    __shared__ unsigned cum[NBIN];             // strictly-higher counts
    __shared__ unsigned chunkH[NBIN / 64];     // 64
    __shared__ unsigned long long stKey[STCAP];
    __shared__ int stIdx[STCAP];
    __shared__ int sTot; __shared__ int sOvf;
    __shared__ int sBstar; __shared__ int sNeed;

    int b   = blockIdx.x / 3;
    int lvl = blockIdx.x % 3;
    int off = (lvl == 0) ? 0 : (lvl == 1) ? OFF1 : OFF2;
    int Nl  = (lvl == 0) ? N0 : (lvl == 1) ? N1 : N2;
    int tid = threadIdx.x;

    const unsigned long long* keys = decKey + (size_t)b * NTOT + off;

    for (int t = tid; t < NBIN; t += 1024) hist[t] = 0;
    if (tid == 0) { sTot = 0; sOvf = 0; }
    __syncthreads();

    for (int t = tid; t < Nl; t += 1024)
        atomicAdd(&hist[(unsigned)(keys[t] >> 33)], 1u);
    __syncthreads();

    if (tid < NBIN / 64) {
        unsigned s = 0;
        for (int j = 0; j < 64; ++j) s += hist[tid * 64 + j];
        chunkH[tid] = s;
    }
    __syncthreads();
    if (tid == 0) {
        unsigned run = 0;
        for (int c = NBIN / 64 - 1; c >= 0; --c) {
            unsigned t = chunkH[c]; chunkH[c] = run; run += t;
        }
    }
    __syncthreads();
    if (tid < NBIN / 64) {
        unsigned run = chunkH[tid];
        for (int q = 63; q >= 0; --q) {
            cum[tid * 64 + q] = run;
            run += hist[tid * 64 + q];
        }
    }
    __syncthreads();

    for (int t = tid; t < NBIN; t += 1024) hist[t] = 0; // becomes cursor/cnt
    __syncthreads();

    for (int t = tid; t < Nl; t += 1024) {
        unsigned long long k = keys[t];
        unsigned bin = (unsigned)(k >> 33);
        if (cum[bin] < (unsigned)TOPN) {
            unsigned c = atomicAdd(&hist[bin], 1u);
            unsigned p = cum[bin] + c;
            atomicAdd(&sTot, 1);
            if (p < STCAP) { stKey[p] = k; stIdx[p] = t; }
            else sOvf = 1;
        }
    }
    __syncthreads();

    auto writeOut = [&](int t, int r) {
        size_t g = (size_t)b * NTOT + off + t;
        unsigned long long k = keys[t];
        float sraw = __uint_as_float((unsigned)(k >> 15));
        int G = off + t;
        // raw-score global key: order among score<=0.05 entries differs from ref
        // but is provably irrelevant (they never keep/suppress/output).
        unsigned long long gk =
            ((unsigned long long)(__float_as_uint(sraw) | 0x80000000u) << 16) |
            (unsigned)(NTOT - G);
        int o = b * NSEL + lvl * TOPN + r;
        selC[o] = decC[g];
        selKey[o] = gk;
        reinterpret_cast<float4*>(selB)[o] = reinterpret_cast<const float4*>(decB)[g];
    };

    if (sOvf == 0) {
        int M = sTot;
        for (int p = tid; p < M; p += 1024) {
            unsigned long long k = stKey[p];
            unsigned bin = (unsigned)(k >> 33);
            unsigned start = cum[bin], end = start + hist[bin];
            int r = (int)start;
            for (unsigned q = start; q < end; ++q) r += (stKey[q] > k) ? 1 : 0;
            if (r < TOPN) writeOut(stIdx[p], r);
        }
    } else {
        // -------- never-expected exact fallback --------
        if (tid == 0) {
            gflagImg[b] = 1;
            int B = 0;
            for (int bin = NBIN - 1; bin >= 0; --bin) {
                if (cum[bin] <= (unsigned)(TOPN - 1) &&
                    cum[bin] + hist[bin] > (unsigned)(TOPN - 1)) { B = bin; break; }
            }
            sBstar = B; sNeed = TOPN - (int)cum[B];
        }
        __syncthreads();
        int Bstar = sBstar, need = sNeed;
        for (int t = tid; t < Nl; t += 1024) {
            unsigned long long k = keys[t];
            int bin = (int)(unsigned)(k >> 33);
            bool em = false;
            if (bin > Bstar) em = true;
            else if (bin == Bstar) {
                int r = 0;
                for (int j = 0; j < Nl; ++j) {
                    unsigned long long kj = keys[j];
                    r += ((int)(unsigned)(kj >> 33) == Bstar && kj > k) ? 1 : 0;
                }
                em = (r < need);
            }
            if (em) {
                int r = atomicAdd(&fbCursor[b * 3 + lvl], 1);
                writeOut(t, r);
            }
        }
    }
}

// ---------------- K3: merge 3 sorted lists -> global sorted order ------------
// 24 blocks: block = (image, level); each ranks its level's 1000 entries.
__global__ __launch_bounds__(256) void k_merge(
    const float* __restrict__ selC, const float* __restrict__ selB,
    const unsigned long long* __restrict__ selKey, const int* __restrict__ gflagImg,
    float* __restrict__ srtS, float* __restrict__ srtC, float* __restrict__ srtB)
{
    __shared__ unsigned long long ks[NSEL]; // 24 KB
    int b   = blockIdx.x / 3;
    int lvl = blockIdx.x % 3;
    int tid = threadIdx.x;
    for (int t = tid; t < NSEL; t += 256) ks[t] = selKey[b * NSEL + t];
    __syncthreads();
    int fb = gflagImg[b];

    for (int q = tid; q < TOPN; q += 256) {
        int t = lvl * TOPN + q;
        unsigned long long k = ks[t];
        int rank;
        if (!fb) {
            rank = q;
            #pragma unroll
            for (int m = 0; m < 3; ++m) {
                if (m == lvl) continue;
                int base = m * TOPN, lo = 0, hi = TOPN;
                while (lo < hi) {
                    int mid = (lo + hi) >> 1;
                    if (ks[base + mid] > k) lo = mid + 1; else hi = mid;
                }
                rank += lo;
            }
        } else {
            int r = 0;
            for (int j = 0; j < NSEL; ++j) r += (ks[j] > k) ? 1 : 0;
            rank = r;
        }
        // transformed score from key: raw = (gk>>16) & 0x7fffffff (scores >= 0)
        float s = __uint_as_float((unsigned)(k >> 16) & 0x7fffffffu);
        int o = b * NSEL + rank;
        srtS[o] = (s > MIN_SCORE_F) ? s : -1.0f;
        srtC[o] = selC[b * NSEL + t];
        reinterpret_cast<float4*>(srtB)[o] =
            reinterpret_cast<const float4*>(selB)[b * NSEL + t];
    }
}

// ---------------- K4a: pairwise suppression masks, register/ballot ----------
// One wave per 64x64 upper-triangle tile. Lane owns column box j in registers;
// row boxes pre-loaded coalesced + shfl-broadcast. rmask is ROW-major padded
// to 48 words (384 B = 6 cache lines per row) so k_resolve's row gather is
// lane-consecutive coalesced. Sub-diagonal words (w < i>>6) are NOT written;
// k_resolve zeroes them at use.
constexpr int NTASK = WPR * (WPR + 1) / 2; // 1128 per image

__global__ __launch_bounds__(256) void k_iou(
    const float* __restrict__ srtB, unsigned long long* __restrict__ rmask)
{
    int wtask = blockIdx.x * 4 + (threadIdx.x >> 6);
    if (wtask >= BATCH * NTASK) return;
    int b = wtask / NTASK;
    int u = wtask % NTASK;
    int r = 0;
    while (u >= WPR - r) { u -= WPR - r; r++; }
    int w = r + u;

    int lane = threadIdx.x & 63;
    int jIdx = w * 64 + lane;
    const float4* Bx = reinterpret_cast<const float4*>(srtB) + (size_t)b * NSEL;

    float4 nobox = make_float4(4e8f, 4e8f, -4e8f, -4e8f); // never intersects
    float4 bj = (jIdx < NSEL) ? Bx[jIdx] : nobox;
    float aj = (bj.z - bj.x) * (bj.w - bj.y);

    int rowBase = r * 64;
    int rIdx = rowBase + lane;
    float4 rowbox = (rIdx < NSEL) ? Bx[rIdx] : nobox;

    unsigned long long rowWord = 0ull;
    #pragma unroll 8
    for (int it = 0; it < 64; ++it) {
        float4 bi;
        bi.x = __shfl(rowbox.x, it);
        bi.y = __shfl(rowbox.y, it);
        bi.z = __shfl(rowbox.z, it);
        bi.w = __shfl(rowbox.w, it);
        float ai = (bi.z - bi.x) * (bi.w - bi.y);
        float xx1 = fmaxf(bi.x, bj.x);
        float yy1 = fmaxf(bi.y, bj.y);
        float xx2 = fminf(bi.z, bj.z);
        float yy2 = fminf(bi.w, bj.w);
        float inter = fmaxf(xx2 - xx1, 0.0f) * fmaxf(yy2 - yy1, 0.0f);
        float uni = ai + aj - inter;
        // exact vs iou>0.5: inter/uni are exact ints < 2^20 in fp32
        bool sup = (inter > 0.5f * uni) && (inter > 0.0f) && (jIdx > rowBase + it);
        unsigned long long word = __ballot(sup);
        if (lane == it) rowWord = word;
    }
    if (rIdx < NSEL)
        rmask[((size_t)b * NSEL + rIdx) * RPW + w] = rowWord;
}

// ---------------- K4b: greedy resolve, shfl-free serial chain ----------------
// One wave per image. Per round: every lane locally replicates the pick scan
// (1 ballot -> word-occupancy mask; word values via LDS broadcast reads; all
// further picks are local ffs/bit-clears -> NO shfl). Gather of WIN mask rows
// is coalesced (row-major rmask). Apply decision = 1 ballot of the owner
// lane's surviving bit (no shfl). Exactly greedy: window = first-WIN avail at
// round start, every window slot consumed -> guaranteed progress.
constexpr int WIN = 8;

__global__ __launch_bounds__(256) void k_resolve(
    const float* __restrict__ srtS, const float* __restrict__ srtC,
    const float* __restrict__ srtB, const unsigned long long* __restrict__ rmask,
    float* __restrict__ out)
{
    __shared__ unsigned long long availLds[WPR]; // live avail bitmap mirror
    __shared__ int keptIdx[MAXDET];
    __shared__ int sPos;

    int b = blockIdx.x, tid = threadIdx.x;
    const unsigned long long* gm = rmask + (size_t)b * NSEL * RPW;
    const float* S = srtS + b * NSEL;

    // valid bitmap: wave w's ballot at iteration k covers word k*4+w
    for (int k = 0; k < 12; ++k) {
        int j = k * 256 + tid;
        float s = (j < NSEL) ? S[j] : -1.0f;
        unsigned long long bal = __ballot(s > MIN_SCORE_F);
        int wIdx = k * 4 + (tid >> 6);
        if ((tid & 63) == 0 && wIdx < WPR) availLds[wIdx] = bal;
    }
    __syncthreads();

    if (tid < 64) {
        int lane = tid;
        unsigned long long validw = (lane < WPR) ? availLds[lane] : 0ull;
        unsigned long long removed = 0ull;
        int pos = 0;
        bool done = false;
        while (!done) {
            // ---- pick first WIN avail (1 ballot + LDS broadcasts, no shfl) ----
            unsigned long long myAvail = validw & ~removed;
            unsigned long long wmask = __ballot(myAvail != 0ull); // word-occupancy
            if (wmask == 0ull) break;
            int ck[WIN];
            int nc = 0;
            {
                int fw = __ffsll(wmask) - 1;
                unsigned long long val = availLds[fw]; // broadcast read (uniform)
                #pragma unroll
                for (int k = 0; k < WIN; ++k) {
                    int bit = __ffsll(val) - 1;
                    ck[k] = fw * 64 + bit;
                    nc = k + 1;
                    val &= val - 1ull;
                    if (val == 0ull) {
                        wmask &= ~(1ull << fw);
                        if (wmask == 0ull) break;
                        fw = __ffsll(wmask) - 1;
                        val = availLds[fw];       // broadcast read (uniform)
                    }
                }
            }

            // ---- concurrent coalesced gather of all window rows ----
            unsigned long long mk[WIN];
            #pragma unroll
            for (int k = 0; k < WIN; ++k) {
                mk[k] = 0ull;
                if (k < nc && lane < WPR && lane >= (ck[k] >> 6))
                    mk[k] = gm[(size_t)ck[k] * RPW + lane];
            }

            // ---- greedy apply within window (ballot decision, no shfl) ----
            #pragma unroll
            for (int k = 0; k < WIN; ++k) {
                if (k >= nc) break;
                int c = ck[k];
                int fw = c >> 6, bit = c & 63;
                unsigned long long aliveBal =
                    __ballot(lane == fw && (((validw & ~removed) >> bit) & 1ull));
                if (aliveBal != 0ull) {               // uniform
                    if (lane == 0) keptIdx[pos] = c;
                    pos++;
                    if (lane == fw) validw &= ~(1ull << bit);
                    removed |= mk[k];
                    if (pos >= MAXDET) { done = true; break; }
                }
            }

            // ---- refresh LDS mirror for next round's picks ----
            if (lane < WPR) availLds[lane] = validw & ~removed;
        }
        if (lane == 0) sPos = pos;
    }
    __syncthreads();

    int pos = sPos;
    const float*  C  = srtC + b * NSEL;
    const float4* Bx = reinterpret_cast<const float4*>(srtB) + (size_t)b * NSEL;
    float* out_s = out + b * MAXDET;
    float* out_c = out + BATCH * MAXDET + b * MAXDET;
    float* out_b = out + 2 * BATCH * MAXDET + (size_t)b * MAXDET * 4;
    for (int t = tid; t < MAXDET; t += 256) {
        if (t < pos) {
            int ki = keptIdx[t];
            float4 bb = Bx[ki];
            out_s[t] = S[ki];
            out_c[t] = C[ki];
            out_b[t * 4 + 0] = bb.x; out_b[t * 4 + 1] = bb.y;
            out_b[t * 4 + 2] = bb.z; out_b[t * 4 + 3] = bb.w;
        } else {
            out_s[t] = -1.0f; out_c[t] = -1.0f;
            out_b[t * 4 + 0] = -1.0f; out_b[t * 4 + 1] = -1.0f;
            out_b[t * 4 + 2] = -1.0f; out_b[t * 4 + 3] = -1.0f;
        }
    }
}

// ---------------- host launcher ----------------
extern "C" void kernel_launch(void* const* d_in, const int* in_sizes, int n_in,
                              void* d_out, int out_size, void* d_ws, size_t ws_size,
                              hipStream_t stream) {
    (void)n_in; (void)out_size; (void)ws_size;

    bool dict = (in_sizes[2] == BATCH * N0 * NUM_CLS); // 693120
    const float *obj[3], *reg[3], *cls[3];
    for (int l = 0; l < 3; ++l) {
        obj[l] = (const float*)d_in[dict ? 4 * l + 0 : l];
        reg[l] = (const float*)d_in[dict ? 4 * l + 1 : 3 + l];
        cls[l] = (const float*)d_in[dict ? 4 * l + 2 : 6 + l];
    }

    char* ws = (char*)d_ws;
    size_t off = 0;
    auto take = [&](size_t bytes) -> void* {
        void* p = ws + off;
        off += (bytes + 255) & ~(size_t)255;
        return p;
    };
    int*                 gflagImg = (int*)take(BATCH * sizeof(int));
    int*                 fbCursor = (int*)take(BATCH * 3 * sizeof(int));
    unsigned long long*  decKey   = (unsigned long long*)take((size_t)BATCH * NTOT * 8);
    float*               decC     = (float*)take((size_t)BATCH * NTOT * 4);
    float*               decB     = (float*)take((size_t)BATCH * NTOT * 16);
    float*               selC     = (float*)take((size_t)BATCH * NSEL * 4);
    float*               selB     = (float*)take((size_t)BATCH * NSEL * 16);
    unsigned long long*  selKey   = (unsigned long long*)take((size_t)BATCH * NSEL * 8);
    float*               srtS     = (float*)take((size_t)BATCH * NSEL * 4);
    float*               srtC     = (float*)take((size_t)BATCH * NSEL * 4);
    float*               srtB     = (float*)take((size_t)BATCH * NSEL * 16);
    unsigned long long*  rmask    = (unsigned long long*)take((size_t)BATCH * NSEL * RPW * 8 + 256);

    int totalDec = BATCH * NTOT; // 181944
    k_decode<<<(totalDec + 255) / 256, 256, 0, stream>>>(
        obj[0], reg[0], cls[0],
        obj[1], reg[1], cls[1],
        obj[2], reg[2], cls[2],
        decKey, decC, decB, gflagImg, fbCursor);

    k_select<<<BATCH * 3, 1024, 0, stream>>>(decKey, decC, decB,
                                             selC, selB, selKey,
                                             gflagImg, fbCursor);

    k_merge<<<BATCH * 3, 256, 0, stream>>>(selC, selB, selKey, gflagImg,
                                           srtS, srtC, srtB);

    int nIouBlocks = (BATCH * NTASK + 3) / 4; // 2256
    k_iou<<<nIouBlocks, 256, 0, stream>>>(srtB, rmask);

    k_resolve<<<BATCH, 256, 0, stream>>>(srtS, srtC, srtB, rmask, (float*)d_out);
}